// Round 1
// baseline (194.775 us; speedup 1.0000x reference)
//
#include <hip/hip_runtime.h>
#include <hip/hip_bf16.h>
#include <stdint.h>

#define BROWS 4096
#define DDIM  1024

typedef __bf16 bf16_t;
typedef __bf16 bf16x8 __attribute__((ext_vector_type(8)));
typedef float  f32x4  __attribute__((ext_vector_type(4)));

__device__ __forceinline__ unsigned short f2bf_bits(float f) {
    union { float f; unsigned int u; } v; v.f = f;
    unsigned int u = v.u;
    // round-to-nearest-even (inputs are finite, no NaN handling needed)
    unsigned int r = (u + 0x7fffu + ((u >> 16) & 1u)) >> 16;
    return (unsigned short)r;
}

// ---------------------------------------------------------------------------
// Kernel 1: prep — per row: log(q)->bf16, p->bf16, e[row]=sum p*log p,
//           kl_div[row] = mean p*(log p - log q)
// One block (256 threads) per row; each thread handles 4 contiguous elems.
// ---------------------------------------------------------------------------
__global__ __launch_bounds__(256) void prep_kernel(
    const float* __restrict__ q, const float* __restrict__ p,
    bf16_t* __restrict__ lqb, bf16_t* __restrict__ pb,
    float* __restrict__ e, float* __restrict__ kld)
{
    const int row = blockIdx.x;
    const int t   = threadIdx.x;
    const float4* q4 = (const float4*)(q + (size_t)row * DDIM);
    const float4* p4 = (const float4*)(p + (size_t)row * DDIM);
    float4 qv = q4[t];
    float4 pv = p4[t];

    float lq0 = __logf(qv.x), lq1 = __logf(qv.y), lq2 = __logf(qv.z), lq3 = __logf(qv.w);
    float lp0 = __logf(pv.x), lp1 = __logf(pv.y), lp2 = __logf(pv.z), lp3 = __logf(pv.w);

    float esum = pv.x * lp0 + pv.y * lp1 + pv.z * lp2 + pv.w * lp3;
    float ksum = pv.x * (lp0 - lq0) + pv.y * (lp1 - lq1)
               + pv.z * (lp2 - lq2) + pv.w * (lp3 - lq3);

    ushort4 uq, up;
    uq.x = f2bf_bits(lq0); uq.y = f2bf_bits(lq1); uq.z = f2bf_bits(lq2); uq.w = f2bf_bits(lq3);
    up.x = f2bf_bits(pv.x); up.y = f2bf_bits(pv.y); up.z = f2bf_bits(pv.z); up.w = f2bf_bits(pv.w);
    ((ushort4*)(lqb + (size_t)row * DDIM))[t] = uq;
    ((ushort4*)(pb  + (size_t)row * DDIM))[t] = up;

    // block reduce (wave64 shuffle + LDS across 4 waves)
    #pragma unroll
    for (int off = 32; off > 0; off >>= 1) {
        esum += __shfl_down(esum, off);
        ksum += __shfl_down(ksum, off);
    }
    __shared__ float se[4], sk[4];
    const int wv = t >> 6, ln = t & 63;
    if (ln == 0) { se[wv] = esum; sk[wv] = ksum; }
    __syncthreads();
    if (t == 0) {
        e[row]   = se[0] + se[1] + se[2] + se[3];
        kld[row] = (sk[0] + sk[1] + sk[2] + sk[3]) * (1.0f / DDIM);
    }
}

// ---------------------------------------------------------------------------
// Kernel 2: cross = log_q @ p^T  (128x128 tile, BK=32, 4 waves, 16x16x32 bf16
// MFMA, global_load_lds width-16 staging) with fused epilogue:
//   CS[i] += sum_j cross[i,j]
//   CL[i] += sum_j cross[i,j]*L[i,j]
//   EL[i] += sum_j e[j]*L[i,j]
// ---------------------------------------------------------------------------
__global__ __launch_bounds__(256) void gemm_epi_kernel(
    const bf16_t* __restrict__ Abf,   // log_q [B,D]
    const bf16_t* __restrict__ Bbf,   // p     [B,D]
    const float*  __restrict__ L,     // labels [B,B]
    const float*  __restrict__ e,     // [B]
    float* __restrict__ CS, float* __restrict__ CL, float* __restrict__ EL)
{
    __shared__ bf16_t As[128 * 32];
    __shared__ bf16_t Bs[128 * 32];

    const int t    = threadIdx.x;
    const int i0   = blockIdx.y * 128;
    const int j0   = blockIdx.x * 128;
    const int wave = t >> 6;
    const int lane = t & 63;
    const int q4   = lane >> 4;      // quad index 0..3
    const int ln   = lane & 15;
    const int wrow = wave >> 1;      // 2x2 wave grid, each wave does 64x64
    const int wcol = wave & 1;

    f32x4 acc[4][4];
    #pragma unroll
    for (int a = 0; a < 4; a++)
        #pragma unroll
        for (int b = 0; b < 4; b++)
            acc[a][b] = (f32x4){0.f, 0.f, 0.f, 0.f};

    // staging: 128x32 bf16 tile = 4096 elems = 512 x 16B; 256 threads x 2
    const int off0 = t * 8;
    const int off1 = (t + 256) * 8;
    const int r0 = off0 >> 5, c0 = off0 & 31;
    const int r1 = off1 >> 5, c1 = off1 & 31;

    for (int k0 = 0; k0 < DDIM; k0 += 32) {
        const bf16_t* gA0 = Abf + (size_t)(i0 + r0) * DDIM + k0 + c0;
        const bf16_t* gA1 = Abf + (size_t)(i0 + r1) * DDIM + k0 + c1;
        const bf16_t* gB0 = Bbf + (size_t)(j0 + r0) * DDIM + k0 + c0;
        const bf16_t* gB1 = Bbf + (size_t)(j0 + r1) * DDIM + k0 + c1;
        __builtin_amdgcn_global_load_lds(
            (const __attribute__((address_space(1))) void*)gA0,
            (__attribute__((address_space(3))) void*)(As + off0), 16, 0, 0);
        __builtin_amdgcn_global_load_lds(
            (const __attribute__((address_space(1))) void*)gA1,
            (__attribute__((address_space(3))) void*)(As + off1), 16, 0, 0);
        __builtin_amdgcn_global_load_lds(
            (const __attribute__((address_space(1))) void*)gB0,
            (__attribute__((address_space(3))) void*)(Bs + off0), 16, 0, 0);
        __builtin_amdgcn_global_load_lds(
            (const __attribute__((address_space(1))) void*)gB1,
            (__attribute__((address_space(3))) void*)(Bs + off1), 16, 0, 0);
        __syncthreads();   // compiler emits vmcnt(0) drain before s_barrier

        bf16x8 af[4], bfr[4];
        #pragma unroll
        for (int mi = 0; mi < 4; mi++)
            af[mi] = *(const bf16x8*)(As + (wrow * 64 + mi * 16 + ln) * 32 + q4 * 8);
        #pragma unroll
        for (int ni = 0; ni < 4; ni++)
            bfr[ni] = *(const bf16x8*)(Bs + (wcol * 64 + ni * 16 + ln) * 32 + q4 * 8);
        #pragma unroll
        for (int mi = 0; mi < 4; mi++)
            #pragma unroll
            for (int ni = 0; ni < 4; ni++)
                acc[mi][ni] = __builtin_amdgcn_mfma_f32_16x16x32_bf16(
                    af[mi], bfr[ni], acc[mi][ni], 0, 0, 0);
        __syncthreads();
    }

    // ---- epilogue: C/D layout is col = lane&15, row = quad*4 + reg ----
    const int i_base = i0 + wrow * 64;
    const int j_base = j0 + wcol * 64;

    float e_j[4];
    #pragma unroll
    for (int ni = 0; ni < 4; ni++) e_j[ni] = e[j_base + ni * 16 + ln];

    #pragma unroll
    for (int mi = 0; mi < 4; mi++) {
        #pragma unroll
        for (int r = 0; r < 4; r++) {
            const int i = i_base + mi * 16 + q4 * 4 + r;
            const float* Lrow = L + (size_t)i * BROWS + j_base;
            float cs = 0.f, cl = 0.f, el = 0.f;
            #pragma unroll
            for (int ni = 0; ni < 4; ni++) {
                float c  = acc[mi][ni][r];
                float Lv = Lrow[ni * 16 + ln];
                cs += c;
                cl += c * Lv;
                el += e_j[ni] * Lv;
            }
            // reduce over the 16 lanes of this quad (xor within low 4 bits)
            #pragma unroll
            for (int s = 1; s < 16; s <<= 1) {
                cs += __shfl_xor(cs, s);
                cl += __shfl_xor(cl, s);
                el += __shfl_xor(el, s);
            }
            if (ln == 0) {
                atomicAdd(&CS[i], cs);
                atomicAdd(&CL[i], cl);
                atomicAdd(&EL[i], el);
            }
        }
    }
}

// ---------------------------------------------------------------------------
// Kernel 3: final — Etot = sum e; result = sum_i pos/neg
// ---------------------------------------------------------------------------
__global__ __launch_bounds__(256) void final_kernel(
    const float* __restrict__ e, const float* __restrict__ kld,
    const float* __restrict__ CS, const float* __restrict__ CL,
    const float* __restrict__ EL, float* __restrict__ out)
{
    __shared__ float sred[4];
    __shared__ float sEtot;
    const int t = threadIdx.x;

    float s = 0.f;
    for (int j = t; j < BROWS; j += 256) s += e[j];
    #pragma unroll
    for (int off = 32; off > 0; off >>= 1) s += __shfl_down(s, off);
    if ((t & 63) == 0) sred[t >> 6] = s;
    __syncthreads();
    if (t == 0) sEtot = sred[0] + sred[1] + sred[2] + sred[3];
    __syncthreads();
    const float Etot = sEtot;
    const float invD = 1.0f / DDIM;

    float rs = 0.f;
    for (int i = t; i < BROWS; i += 256) {
        float el = EL[i], cl = CL[i], cs = CS[i];
        float pos = kld[i] + (el - cl) * invD;
        float neg = (Etot - el - cs + cl) * invD;
        rs += pos / neg;
    }
    __syncthreads();
    #pragma unroll
    for (int off = 32; off > 0; off >>= 1) rs += __shfl_down(rs, off);
    if ((t & 63) == 0) sred[t >> 6] = rs;
    __syncthreads();
    if (t == 0) out[0] = sred[0] + sred[1] + sred[2] + sred[3];
}

// ---------------------------------------------------------------------------
extern "C" void kernel_launch(void* const* d_in, const int* in_sizes, int n_in,
                              void* d_out, int out_size, void* d_ws, size_t ws_size,
                              hipStream_t stream)
{
    const float* q = (const float*)d_in[0];
    const float* p = (const float*)d_in[1];
    const float* L = (const float*)d_in[2];
    float* out = (float*)d_out;

    char* ws = (char*)d_ws;
    bf16_t* lqb = (bf16_t*)ws;                                   // 8 MB
    bf16_t* pb  = (bf16_t*)(ws + (size_t)BROWS * DDIM * 2);      // 8 MB
    float*  e   = (float*)(ws + (size_t)BROWS * DDIM * 4);       // 16 KB
    float*  kld = e + BROWS;                                     // 16 KB
    float*  CS  = kld + BROWS;                                   // 16 KB
    float*  CL  = CS + BROWS;                                    // 16 KB
    float*  EL  = CL + BROWS;                                    // 16 KB

    // ws is re-poisoned to 0xAA before every timed launch — zero accumulators
    hipMemsetAsync(CS, 0, 3 * BROWS * sizeof(float), stream);

    prep_kernel<<<BROWS, 256, 0, stream>>>(q, p, lqb, pb, e, kld);

    dim3 grid(BROWS / 128, BROWS / 128);
    gemm_epi_kernel<<<grid, 256, 0, stream>>>(lqb, pb, L, e, CS, CL, EL);

    final_kernel<<<1, 256, 0, stream>>>(e, kld, CS, CL, EL, out);
}

// Round 2
// 194.165 us; speedup vs baseline: 1.0031x; 1.0031x over previous
//
#include <hip/hip_runtime.h>
#include <hip/hip_bf16.h>
#include <stdint.h>

#define BROWS 4096
#define DDIM  1024

typedef __bf16 bf16_t;
typedef __bf16 bf16x8 __attribute__((ext_vector_type(8)));
typedef float  f32x4  __attribute__((ext_vector_type(4)));

__device__ __forceinline__ unsigned short f2bf_bits(float f) {
    union { float f; unsigned int u; } v; v.f = f;
    unsigned int u = v.u;
    unsigned int r = (u + 0x7fffu + ((u >> 16) & 1u)) >> 16;
    return (unsigned short)r;
}

// ---------------------------------------------------------------------------
// Kernel 1: prep — per row: log(q)->bf16, p->bf16, e[row]=sum p*log p,
//           kl_div[row] = mean p*(log p - log q). Also zeroes CS/CL/EL[row]
//           (replaces a separate memset dispatch).
// ---------------------------------------------------------------------------
__global__ __launch_bounds__(256) void prep_kernel(
    const float* __restrict__ q, const float* __restrict__ p,
    bf16_t* __restrict__ lqb, bf16_t* __restrict__ pb,
    float* __restrict__ e, float* __restrict__ kld,
    float* __restrict__ CS, float* __restrict__ CL, float* __restrict__ EL)
{
    const int row = blockIdx.x;
    const int t   = threadIdx.x;
    const float4* q4 = (const float4*)(q + (size_t)row * DDIM);
    const float4* p4 = (const float4*)(p + (size_t)row * DDIM);
    float4 qv = q4[t];
    float4 pv = p4[t];

    float lq0 = __logf(qv.x), lq1 = __logf(qv.y), lq2 = __logf(qv.z), lq3 = __logf(qv.w);
    float lp0 = __logf(pv.x), lp1 = __logf(pv.y), lp2 = __logf(pv.z), lp3 = __logf(pv.w);

    float esum = pv.x * lp0 + pv.y * lp1 + pv.z * lp2 + pv.w * lp3;
    float ksum = pv.x * (lp0 - lq0) + pv.y * (lp1 - lq1)
               + pv.z * (lp2 - lq2) + pv.w * (lp3 - lq3);

    ushort4 uq, up;
    uq.x = f2bf_bits(lq0); uq.y = f2bf_bits(lq1); uq.z = f2bf_bits(lq2); uq.w = f2bf_bits(lq3);
    up.x = f2bf_bits(pv.x); up.y = f2bf_bits(pv.y); up.z = f2bf_bits(pv.z); up.w = f2bf_bits(pv.w);
    ((ushort4*)(lqb + (size_t)row * DDIM))[t] = uq;
    ((ushort4*)(pb  + (size_t)row * DDIM))[t] = up;

    if (t == 0) { CS[row] = 0.f; CL[row] = 0.f; EL[row] = 0.f; }

    #pragma unroll
    for (int off = 32; off > 0; off >>= 1) {
        esum += __shfl_down(esum, off);
        ksum += __shfl_down(ksum, off);
    }
    __shared__ float se[4], sk[4];
    const int wv = t >> 6, ln = t & 63;
    if (ln == 0) { se[wv] = esum; sk[wv] = ksum; }
    __syncthreads();
    if (t == 0) {
        e[row]   = se[0] + se[1] + se[2] + se[3];
        kld[row] = (sk[0] + sk[1] + sk[2] + sk[3]) * (1.0f / DDIM);
    }
}

// ---------------------------------------------------------------------------
// Kernel 2: cross = log_q @ p^T, 128x128 tile, BK=32, DOUBLE-BUFFERED LDS:
//   loads for tile k+1 are issued before compute on tile k; ONE barrier/iter.
//   Fused epilogue reduces CS/CL/EL row-partials (labels read non-temporal).
// ---------------------------------------------------------------------------
__global__ __launch_bounds__(256) void gemm_epi_kernel(
    const bf16_t* __restrict__ Abf,   // log_q [B,D]
    const bf16_t* __restrict__ Bbf,   // p     [B,D]
    const float*  __restrict__ L,     // labels [B,B]
    const float*  __restrict__ e,     // [B]
    float* __restrict__ CS, float* __restrict__ CL, float* __restrict__ EL)
{
    __shared__ bf16_t As[2][128 * 32];   // 8 KB per buffer
    __shared__ bf16_t Bs[2][128 * 32];

    const int t    = threadIdx.x;
    const int i0   = blockIdx.y * 128;
    const int j0   = blockIdx.x * 128;
    const int wave = t >> 6;
    const int lane = t & 63;
    const int q4   = lane >> 4;
    const int ln   = lane & 15;
    const int wrow = wave >> 1;
    const int wcol = wave & 1;

    f32x4 acc[4][4];
    #pragma unroll
    for (int a = 0; a < 4; a++)
        #pragma unroll
        for (int b = 0; b < 4; b++)
            acc[a][b] = (f32x4){0.f, 0.f, 0.f, 0.f};

    // staging geometry: 128x32 bf16 tile = 512 x 16B chunks; 256 threads x 2
    const int off0 = t * 8;
    const int off1 = off0 + 2048;
    const int r0 = off0 >> 5, c0 = off0 & 31;
    const int r1 = off1 >> 5, c1 = off1 & 31;

    const bf16_t* gA0 = Abf + (size_t)(i0 + r0) * DDIM + c0;
    const bf16_t* gA1 = Abf + (size_t)(i0 + r1) * DDIM + c1;
    const bf16_t* gB0 = Bbf + (size_t)(j0 + r0) * DDIM + c0;
    const bf16_t* gB1 = Bbf + (size_t)(j0 + r1) * DDIM + c1;

    auto stage = [&](int k0, int buf) {
        __builtin_amdgcn_global_load_lds(
            (const __attribute__((address_space(1))) void*)(gA0 + k0),
            (__attribute__((address_space(3))) void*)(&As[buf][off0]), 16, 0, 0);
        __builtin_amdgcn_global_load_lds(
            (const __attribute__((address_space(1))) void*)(gA1 + k0),
            (__attribute__((address_space(3))) void*)(&As[buf][off1]), 16, 0, 0);
        __builtin_amdgcn_global_load_lds(
            (const __attribute__((address_space(1))) void*)(gB0 + k0),
            (__attribute__((address_space(3))) void*)(&Bs[buf][off0]), 16, 0, 0);
        __builtin_amdgcn_global_load_lds(
            (const __attribute__((address_space(1))) void*)(gB1 + k0),
            (__attribute__((address_space(3))) void*)(&Bs[buf][off1]), 16, 0, 0);
    };

    stage(0, 0);
    __syncthreads();   // tile 0 resident

    #pragma unroll 1
    for (int it = 0; it < DDIM / 32; ++it) {
        const int cur = it & 1;
        const int knext = (it + 1) * 32;
        if (knext < DDIM) stage(knext, cur ^ 1);   // in flight during compute

        bf16x8 af[4], bfr[4];
        #pragma unroll
        for (int mi = 0; mi < 4; mi++)
            af[mi] = *(const bf16x8*)(&As[cur][(wrow * 64 + mi * 16 + ln) * 32 + q4 * 8]);
        #pragma unroll
        for (int ni = 0; ni < 4; ni++)
            bfr[ni] = *(const bf16x8*)(&Bs[cur][(wcol * 64 + ni * 16 + ln) * 32 + q4 * 8]);
        #pragma unroll
        for (int mi = 0; mi < 4; mi++)
            #pragma unroll
            for (int ni = 0; ni < 4; ni++)
                acc[mi][ni] = __builtin_amdgcn_mfma_f32_16x16x32_bf16(
                    af[mi], bfr[ni], acc[mi][ni], 0, 0, 0);

        __syncthreads();   // drains lgkm (frag reads done) + vmcnt (next tile landed)
    }

    // ---- epilogue: C/D layout col = lane&15, row = quad*4 + reg ----
    const int i_base = i0 + wrow * 64;
    const int j_base = j0 + wcol * 64;

    float e_j[4];
    #pragma unroll
    for (int ni = 0; ni < 4; ni++) e_j[ni] = e[j_base + ni * 16 + ln];

    #pragma unroll
    for (int mi = 0; mi < 4; mi++) {
        #pragma unroll
        for (int r = 0; r < 4; r++) {
            const int i = i_base + mi * 16 + q4 * 4 + r;
            const float* Lrow = L + (size_t)i * BROWS + j_base;
            float cs = 0.f, cl = 0.f, el = 0.f;
            #pragma unroll
            for (int ni = 0; ni < 4; ni++) {
                float c  = acc[mi][ni][r];
                float Lv = __builtin_nontemporal_load(Lrow + ni * 16 + ln);
                cs += c;
                cl += c * Lv;
                el += e_j[ni] * Lv;
            }
            #pragma unroll
            for (int s = 1; s < 16; s <<= 1) {
                cs += __shfl_xor(cs, s);
                cl += __shfl_xor(cl, s);
                el += __shfl_xor(el, s);
            }
            if (ln == 0) {
                atomicAdd(&CS[i], cs);
                atomicAdd(&CL[i], cl);
                atomicAdd(&EL[i], el);
            }
        }
    }
}

// ---------------------------------------------------------------------------
// Kernel 3: final — Etot = sum e; result = sum_i pos/neg
// ---------------------------------------------------------------------------
__global__ __launch_bounds__(256) void final_kernel(
    const float* __restrict__ e, const float* __restrict__ kld,
    const float* __restrict__ CS, const float* __restrict__ CL,
    const float* __restrict__ EL, float* __restrict__ out)
{
    __shared__ float sred[4];
    __shared__ float sEtot;
    const int t = threadIdx.x;

    float s = 0.f;
    for (int j = t; j < BROWS; j += 256) s += e[j];
    #pragma unroll
    for (int off = 32; off > 0; off >>= 1) s += __shfl_down(s, off);
    if ((t & 63) == 0) sred[t >> 6] = s;
    __syncthreads();
    if (t == 0) sEtot = sred[0] + sred[1] + sred[2] + sred[3];
    __syncthreads();
    const float Etot = sEtot;
    const float invD = 1.0f / DDIM;

    float rs = 0.f;
    for (int i = t; i < BROWS; i += 256) {
        float el = EL[i], cl = CL[i], cs = CS[i];
        float pos = kld[i] + (el - cl) * invD;
        float neg = (Etot - el - cs + cl) * invD;
        rs += pos / neg;
    }
    __syncthreads();
    #pragma unroll
    for (int off = 32; off > 0; off >>= 1) rs += __shfl_down(rs, off);
    if ((t & 63) == 0) sred[t >> 6] = rs;
    __syncthreads();
    if (t == 0) out[0] = sred[0] + sred[1] + sred[2] + sred[3];
}

// ---------------------------------------------------------------------------
extern "C" void kernel_launch(void* const* d_in, const int* in_sizes, int n_in,
                              void* d_out, int out_size, void* d_ws, size_t ws_size,
                              hipStream_t stream)
{
    const float* q = (const float*)d_in[0];
    const float* p = (const float*)d_in[1];
    const float* L = (const float*)d_in[2];
    float* out = (float*)d_out;

    char* ws = (char*)d_ws;
    bf16_t* lqb = (bf16_t*)ws;                                   // 8 MB
    bf16_t* pb  = (bf16_t*)(ws + (size_t)BROWS * DDIM * 2);      // 8 MB
    float*  e   = (float*)(ws + (size_t)BROWS * DDIM * 4);       // 16 KB
    float*  kld = e + BROWS;                                     // 16 KB
    float*  CS  = kld + BROWS;                                   // 16 KB
    float*  CL  = CS + BROWS;                                    // 16 KB
    float*  EL  = CL + BROWS;                                    // 16 KB

    prep_kernel<<<BROWS, 256, 0, stream>>>(q, p, lqb, pb, e, kld, CS, CL, EL);

    dim3 grid(BROWS / 128, BROWS / 128);
    gemm_epi_kernel<<<grid, 256, 0, stream>>>(lqb, pb, L, e, CS, CL, EL);

    final_kernel<<<1, 256, 0, stream>>>(e, kld, CS, CL, EL, out);
}